// Round 1
// baseline (234.037 us; speedup 1.0000x reference)
//
#include <hip/hip_runtime.h>
#include <stdint.h>
#include <stddef.h>

#define T_ 2048
#define D_ 1024
#define H_ 16

typedef __attribute__((ext_vector_type(8))) short short8;
typedef __attribute__((ext_vector_type(4))) float f32x4;

__device__ __forceinline__ unsigned short f2bf(float f){
  union { float f; unsigned u; } c; c.f = f;
  unsigned u = c.u;
  return (unsigned short)((u + 0x7fffu + ((u >> 16) & 1u)) >> 16);
}

__device__ __forceinline__ f32x4 mfma16(short8 a, short8 b, f32x4 c){
  return __builtin_amdgcn_mfma_f32_16x16x32_bf16(a, b, c, 0, 0, 0);
}

// ---------------- prep: f32 -> bf16 conversions ----------------
__global__ __launch_bounds__(256) void k_prep(const float* __restrict__ x,
    const float* __restrict__ wq, const float* __restrict__ wk,
    const float* __restrict__ wv, const float* __restrict__ wo,
    unsigned short* __restrict__ xb, unsigned short* __restrict__ wqkv,
    unsigned short* __restrict__ wob)
{
  const long long NX = 4194304LL, NW = 1048576LL;
  long long base = ((long long)blockIdx.x * 256 + threadIdx.x) * 4;
  const float* s; unsigned short* d;
  if (base < NX){ s = x + base; d = xb + base; }
  else if (base < NX + 3*NW){
    long long j = base - NX;
    if (j < NW) s = wq + j;
    else if (j < 2*NW) s = wk + (j - NW);
    else s = wv + (j - 2*NW);
    d = wqkv + j;
  } else if (base < NX + 4*NW){
    long long j = base - NX - 3*NW;
    s = wo + j; d = wob + j;
  } else return;
  float4 v = *(const float4*)s;
  d[0] = f2bf(v.x); d[1] = f2bf(v.y); d[2] = f2bf(v.z); d[3] = f2bf(v.w);
}

// ---------------- rope sin/cos table [T][32] ----------------
__global__ __launch_bounds__(256) void k_rope(float* __restrict__ tab){
  int i = blockIdx.x * 256 + threadIdx.x;
  if (i >= T_ * 32) return;
  int t = i >> 5, p = i & 31;
  float ang = (float)t * powf(10000.0f, -(float)p * (1.0f / 32.0f));
  tab[i] = sinf(ang);
  tab[T_ * 32 + i] = cosf(ang);
}

// ---------------- shared GEMM core: C[128x128] = A[128xK] * B[128xK]^T ----------------
// A row-major [M][1024], Bm row-major [N][1024] (i.e. computes A @ Bm^T).
// LDS XOR-swizzle: 64-elem (128B) rows, 8 slots of 16B, slot ^= (row&7).
__device__ __forceinline__ void gemm_core(const unsigned short* __restrict__ A,
    const unsigned short* __restrict__ Bm, int m0, int n0,
    unsigned short* lA, unsigned short* lB, f32x4 (&acc)[4][4])
{
  const int tid = threadIdx.x, lane = tid & 63, wave = tid >> 6;
  const int wr = wave >> 1, wc = wave & 1;
  for (int mi = 0; mi < 4; ++mi)
    for (int ni = 0; ni < 4; ++ni)
      acc[mi][ni] = (f32x4){0.f, 0.f, 0.f, 0.f};
  for (int k0 = 0; k0 < 1024; k0 += 64){
    __syncthreads();
#pragma unroll
    for (int p = 0; p < 4; ++p){
      int c = p * 256 + tid, r = c >> 3, s = c & 7;
      int dso = r * 64 + ((s ^ (r & 7)) << 3);
      *(short8*)(lA + dso) = *(const short8*)(A + (size_t)(m0 + r) * 1024 + k0 + s * 8);
      *(short8*)(lB + dso) = *(const short8*)(Bm + (size_t)(n0 + r) * 1024 + k0 + s * 8);
    }
    __syncthreads();
#pragma unroll
    for (int kk = 0; kk < 2; ++kk){
      int kslot = kk * 4 + (lane >> 4);
      short8 af[4], bf[4];
#pragma unroll
      for (int mi = 0; mi < 4; ++mi){
        int row = wr * 64 + mi * 16 + (lane & 15);
        af[mi] = *(const short8*)(lA + row * 64 + ((kslot ^ (row & 7)) << 3));
      }
#pragma unroll
      for (int ni = 0; ni < 4; ++ni){
        int row = wc * 64 + ni * 16 + (lane & 15);
        bf[ni] = *(const short8*)(lB + row * 64 + ((kslot ^ (row & 7)) << 3));
      }
#pragma unroll
      for (int mi = 0; mi < 4; ++mi)
#pragma unroll
        for (int ni = 0; ni < 4; ++ni)
          acc[mi][ni] = mfma16(af[mi], bf[ni], acc[mi][ni]);
    }
  }
}

// ---------------- fused QKV projection + bias + RoPE ----------------
__global__ __launch_bounds__(256) void k_qkv(const unsigned short* __restrict__ xb,
    const unsigned short* __restrict__ wqkv,
    const float* __restrict__ bq, const float* __restrict__ bk, const float* __restrict__ bv,
    const float* __restrict__ tab,
    unsigned short* __restrict__ Qw, unsigned short* __restrict__ Kw,
    unsigned short* __restrict__ Vw)
{
  __shared__ alignas(16) unsigned short lA[128 * 64];
  __shared__ alignas(16) unsigned short lB[128 * 64];
  int m0 = blockIdx.y * 128, n0 = blockIdx.x * 128;
  f32x4 acc[4][4];
  gemm_core(xb, wqkv, m0, n0, lA, lB, acc);
  int lane = threadIdx.x & 63, wave = threadIdx.x >> 6;
  int wr = wave >> 1, wc = wave & 1;
  int mat = n0 >> 10;                       // 0=Q 1=K 2=V (128 | 1024)
  const float* bias = (mat == 0) ? bq : (mat == 1 ? bk : bv);
  unsigned short* Out = (mat == 0) ? Qw : (mat == 1 ? Kw : Vw);
  const float* st = tab; const float* ct = tab + T_ * 32;
  for (int mi = 0; mi < 4; ++mi){
    for (int ni = 0; ni < 4; ++ni){
      int col = n0 + wc * 64 + ni * 16 + (lane & 15);
      int nn = col & 1023, h = nn >> 6, dd = nn & 63;
      float bsv = bias[nn];
      f32x4 v4 = acc[mi][ni];
#pragma unroll
      for (int r = 0; r < 4; ++r){
        int m = m0 + wr * 64 + mi * 16 + ((lane >> 4) << 2) + r;
        int bb = m >> 11, t = m & 2047;
        float v = v4[r] + bsv;
        float res;
        if (mat < 2){
          float u = __shfl_xor(v, 1);       // partner col (2p <-> 2p+1) is lane^1
          int p = dd >> 1;
          float sv = st[t * 32 + p], cv = ct[t * 32 + p];
          res = (dd & 1) ? (u * sv + v * cv) : (v * cv - u * sv);
        } else res = v;
        Out[((size_t)(bb * H_ + h) * T_ + t) * 64 + dd] = f2bf(res);
      }
    }
  }
}

// ---------------- flash attention (causal), [B,H,T,DK] bf16 in, ctx bf16 out ----------------
__global__ __launch_bounds__(256) void k_attn(const unsigned short* __restrict__ Qw,
    const unsigned short* __restrict__ Kw, const unsigned short* __restrict__ Vw,
    unsigned short* __restrict__ ctxb)
{
  __shared__ alignas(16) unsigned short Kl[64 * 64];       // [j][d], swizzled
  __shared__ alignas(16) unsigned short Vt[64 * 64];       // [d][j], swizzled
  __shared__ alignas(16) unsigned short Pl[4][32 * 64];    // per-wave P [i][j], swizzled
  int qt = blockIdx.x, bh = blockIdx.y;
  int tid = threadIdx.x, lane = tid & 63, wave = tid >> 6;
  const unsigned short* Qb = Qw + (size_t)bh * T_ * 64;
  const unsigned short* Kb = Kw + (size_t)bh * T_ * 64;
  const unsigned short* Vb = Vw + (size_t)bh * T_ * 64;
  int q0 = qt * 128 + wave * 32;            // this wave's 32 q-rows

  short8 qf[2][2];
#pragma unroll
  for (int mi = 0; mi < 2; ++mi){
    const unsigned short* qp = Qb + (size_t)(q0 + mi * 16 + (lane & 15)) * 64 + ((lane >> 4) << 3);
    qf[mi][0] = *(const short8*)qp;
    qf[mi][1] = *(const short8*)(qp + 32);
  }
  float mr[2][4], lr[2][4];
  f32x4 acc_o[2][4];
  for (int mi = 0; mi < 2; ++mi)
    for (int r = 0; r < 4; ++r){ mr[mi][r] = -1e30f; lr[mi][r] = 0.f; }
  for (int mi = 0; mi < 2; ++mi)
    for (int df = 0; df < 4; ++df) acc_o[mi][df] = (f32x4){0.f, 0.f, 0.f, 0.f};

  int ntiles = 2 * qt + 2;
  for (int jt = 0; jt < ntiles; ++jt){
    int j0 = jt * 64;
    __syncthreads();
#pragma unroll
    for (int p = 0; p < 2; ++p){
      int c = p * 256 + tid, r = c >> 3, s = c & 7;
      *(short8*)(Kl + r * 64 + ((s ^ (r & 7)) << 3)) =
          *(const short8*)(Kb + (size_t)(j0 + r) * 64 + s * 8);
      short8 vv = *(const short8*)(Vb + (size_t)(j0 + r) * 64 + s * 8);
#pragma unroll
      for (int e0 = 0; e0 < 8; ++e0){
        int e = (e0 + s) & 7;               // rotated order -> spread banks
        int dd = s * 8 + e;
        Vt[dd * 64 + (((r >> 3) ^ (dd & 7)) << 3) + (r & 7)] = (unsigned short)vv[e];
      }
    }
    __syncthreads();
    if (j0 <= q0 + 31){                     // wave-level causal skip
      bool need_mask = (j0 + 63 > q0);
      f32x4 accs[2][4];
      for (int mi = 0; mi < 2; ++mi)
        for (int jf = 0; jf < 4; ++jf) accs[mi][jf] = (f32x4){0.f, 0.f, 0.f, 0.f};
#pragma unroll
      for (int kk = 0; kk < 2; ++kk){
        int kslot = kk * 4 + (lane >> 4);
        short8 kf[4];
#pragma unroll
        for (int jf = 0; jf < 4; ++jf){
          int row = jf * 16 + (lane & 15);
          kf[jf] = *(const short8*)(Kl + row * 64 + ((kslot ^ (row & 7)) << 3));
        }
#pragma unroll
        for (int mi = 0; mi < 2; ++mi)
#pragma unroll
          for (int jf = 0; jf < 4; ++jf)
            accs[mi][jf] = mfma16(qf[mi][kk], kf[jf], accs[mi][jf]);
      }
#pragma unroll
      for (int mi = 0; mi < 2; ++mi){
        float pv[4][4];
#pragma unroll
        for (int jf = 0; jf < 4; ++jf)
#pragma unroll
          for (int r = 0; r < 4; ++r){
            float sv = accs[mi][jf][r] * 0.125f;
            if (need_mask){
              int ra = q0 + mi * 16 + ((lane >> 4) << 2) + r;
              int ca = j0 + jf * 16 + (lane & 15);
              sv = (ca > ra) ? -1e30f : sv;
            }
            pv[jf][r] = sv;
          }
        float scl[4];
#pragma unroll
        for (int r = 0; r < 4; ++r){
          float mt = fmaxf(fmaxf(pv[0][r], pv[1][r]), fmaxf(pv[2][r], pv[3][r]));
          mt = fmaxf(mt, __shfl_xor(mt, 1));
          mt = fmaxf(mt, __shfl_xor(mt, 2));
          mt = fmaxf(mt, __shfl_xor(mt, 4));
          mt = fmaxf(mt, __shfl_xor(mt, 8));
          float mn = fmaxf(mr[mi][r], mt);
          float sc = __expf(mr[mi][r] - mn);
          mr[mi][r] = mn;
          float rs = 0.f;
#pragma unroll
          for (int jf = 0; jf < 4; ++jf){
            float pe = __expf(pv[jf][r] - mn);
            pv[jf][r] = pe;
            rs += pe;
          }
          rs += __shfl_xor(rs, 1);
          rs += __shfl_xor(rs, 2);
          rs += __shfl_xor(rs, 4);
          rs += __shfl_xor(rs, 8);
          lr[mi][r] = lr[mi][r] * sc + rs;
          scl[r] = sc;
        }
#pragma unroll
        for (int df = 0; df < 4; ++df){
          f32x4 a = acc_o[mi][df];
          a[0] *= scl[0]; a[1] *= scl[1]; a[2] *= scl[2]; a[3] *= scl[3];
          acc_o[mi][df] = a;
        }
#pragma unroll
        for (int jf = 0; jf < 4; ++jf)
#pragma unroll
          for (int r = 0; r < 4; ++r){
            int row = mi * 16 + ((lane >> 4) << 2) + r;
            int j = jf * 16 + (lane & 15);
            Pl[wave][row * 64 + (((j >> 3) ^ (row & 7)) << 3) + (j & 7)] = f2bf(pv[jf][r]);
          }
      }
      // PV: ctx += P @ V   (A = P from Pl, B = V from Vt[d][j])
#pragma unroll
      for (int kk = 0; kk < 2; ++kk){
        int jslot = kk * 4 + (lane >> 4);
        short8 pa[2];
#pragma unroll
        for (int mi = 0; mi < 2; ++mi){
          int row = mi * 16 + (lane & 15);
          pa[mi] = *(const short8*)(&Pl[wave][row * 64 + ((jslot ^ (row & 7)) << 3)]);
        }
#pragma unroll
        for (int df = 0; df < 4; ++df){
          int dd = df * 16 + (lane & 15);
          short8 vf = *(const short8*)(Vt + dd * 64 + ((jslot ^ (dd & 7)) << 3));
#pragma unroll
          for (int mi = 0; mi < 2; ++mi)
            acc_o[mi][df] = mfma16(pa[mi], vf, acc_o[mi][df]);
        }
      }
    }
  }
  int bb = bh >> 4, h = bh & 15;
#pragma unroll
  for (int mi = 0; mi < 2; ++mi)
#pragma unroll
    for (int df = 0; df < 4; ++df){
      f32x4 a = acc_o[mi][df];
#pragma unroll
      for (int r = 0; r < 4; ++r){
        int t = q0 + mi * 16 + ((lane >> 4) << 2) + r;
        int dd = df * 16 + (lane & 15);
        ctxb[((size_t)(bb * T_ + t)) * 1024 + h * 64 + dd] = f2bf(a[r] / lr[mi][r]);
      }
    }
}

// ---------------- output projection ----------------
__global__ __launch_bounds__(256) void k_oproj(const unsigned short* __restrict__ ctxb,
    const unsigned short* __restrict__ wob, const float* __restrict__ bo,
    float* __restrict__ out)
{
  __shared__ alignas(16) unsigned short lA[128 * 64];
  __shared__ alignas(16) unsigned short lB[128 * 64];
  int m0 = blockIdx.y * 128, n0 = blockIdx.x * 128;
  f32x4 acc[4][4];
  gemm_core(ctxb, wob, m0, n0, lA, lB, acc);
  int lane = threadIdx.x & 63, wave = threadIdx.x >> 6;
  int wr = wave >> 1, wc = wave & 1;
  for (int mi = 0; mi < 4; ++mi)
    for (int ni = 0; ni < 4; ++ni){
      int col = n0 + wc * 64 + ni * 16 + (lane & 15);
      float bsv = bo[col];
      f32x4 v4 = acc[mi][ni];
#pragma unroll
      for (int r = 0; r < 4; ++r){
        int m = m0 + wr * 64 + mi * 16 + ((lane >> 4) << 2) + r;
        out[(size_t)m * 1024 + col] = v4[r] + bsv;
      }
    }
}

extern "C" void kernel_launch(void* const* d_in, const int* in_sizes, int n_in,
                              void* d_out, int out_size, void* d_ws, size_t ws_size,
                              hipStream_t stream)
{
  const float* x  = (const float*)d_in[0];
  const float* wq = (const float*)d_in[1];
  const float* bq = (const float*)d_in[2];
  const float* wk = (const float*)d_in[3];
  const float* bk = (const float*)d_in[4];
  const float* wv = (const float*)d_in[5];
  const float* bv = (const float*)d_in[6];
  const float* wo = (const float*)d_in[7];
  const float* bo = (const float*)d_in[8];
  char* w = (char*)d_ws;
  unsigned short* xb   = (unsigned short*)(w);               // 8 MiB  [4096][1024]
  unsigned short* wqkv = (unsigned short*)(w + (8 << 20));   // 6 MiB  [3072][1024]
  unsigned short* wob  = (unsigned short*)(w + (14 << 20));  // 2 MiB  [1024][1024]
  unsigned short* Qw   = (unsigned short*)(w + (16 << 20));  // 8 MiB  [B,H,T,DK]
  unsigned short* Kw   = (unsigned short*)(w + (24 << 20));  // 8 MiB
  unsigned short* Vw   = (unsigned short*)(w + (32 << 20));  // 8 MiB
  unsigned short* ctxb = (unsigned short*)(w + (40 << 20));  // 8 MiB  [B,T,D]
  float* tab           = (float*)(w + (48 << 20));           // 512 KiB sin|cos

  k_prep<<<8192, 256, 0, stream>>>(x, wq, wk, wv, wo, xb, wqkv, wob);
  k_rope<<<256, 256, 0, stream>>>(tab);
  k_qkv<<<dim3(24, 32), 256, 0, stream>>>(xb, wqkv, bq, bk, bv, tab, Qw, Kw, Vw);
  k_attn<<<dim3(16, 32), 256, 0, stream>>>(Qw, Kw, Vw, ctxb);
  k_oproj<<<dim3(8, 32), 256, 0, stream>>>(ctxb, wob, bo, (float*)d_out);
}

// Round 2
// 148.363 us; speedup vs baseline: 1.5775x; 1.5775x over previous
//
#include <hip/hip_runtime.h>
#include <stdint.h>
#include <stddef.h>

#define T_ 2048
#define D_ 1024
#define H_ 16

typedef __attribute__((ext_vector_type(8))) short short8;
typedef __attribute__((ext_vector_type(4))) float f32x4;
typedef __attribute__((ext_vector_type(4))) short s16x4;

__device__ __forceinline__ unsigned short f2bf(float f){
  union { float f; unsigned u; } c; c.f = f;
  unsigned u = c.u;
  return (unsigned short)((u + 0x7fffu + ((u >> 16) & 1u)) >> 16);
}

__device__ __forceinline__ unsigned pk_bf16(float lo, float hi){
  unsigned r;
  asm("v_cvt_pk_bf16_f32 %0, %1, %2" : "=v"(r) : "v"(lo), "v"(hi));
  return r;
}

__device__ __forceinline__ float fexp2(float x){
#if __has_builtin(__builtin_amdgcn_exp2f)
  return __builtin_amdgcn_exp2f(x);
#else
  return exp2f(x);
#endif
}

__device__ __forceinline__ f32x4 mfma16(short8 a, short8 b, f32x4 c){
  return __builtin_amdgcn_mfma_f32_16x16x32_bf16(a, b, c, 0, 0, 0);
}

// async global->LDS, 16B per lane; LDS dest must be uniform-base + lane*16
__device__ __forceinline__ void gload16(const void* g, void* l){
  __builtin_amdgcn_global_load_lds(
      (const __attribute__((address_space(1))) unsigned*)g,
      (__attribute__((address_space(3))) unsigned*)l, 16, 0, 0);
}

// ---------------- prep: f32 -> bf16 conversions ----------------
__global__ __launch_bounds__(256) void k_prep(const float* __restrict__ x,
    const float* __restrict__ wq, const float* __restrict__ wk,
    const float* __restrict__ wv, const float* __restrict__ wo,
    unsigned short* __restrict__ xb, unsigned short* __restrict__ wqkv,
    unsigned short* __restrict__ wob)
{
  const long long NX = 4194304LL, NW = 1048576LL;
  long long base = ((long long)blockIdx.x * 256 + threadIdx.x) * 4;
  const float* s; unsigned short* d;
  if (base < NX){ s = x + base; d = xb + base; }
  else if (base < NX + 3*NW){
    long long j = base - NX;
    if (j < NW) s = wq + j;
    else if (j < 2*NW) s = wk + (j - NW);
    else s = wv + (j - 2*NW);
    d = wqkv + j;
  } else if (base < NX + 4*NW){
    long long j = base - NX - 3*NW;
    s = wo + j; d = wob + j;
  } else return;
  float4 v = *(const float4*)s;
  d[0] = f2bf(v.x); d[1] = f2bf(v.y); d[2] = f2bf(v.z); d[3] = f2bf(v.w);
}

// ---------------- rope sin/cos table [T][32] ----------------
__global__ __launch_bounds__(256) void k_rope(float* __restrict__ tab){
  int i = blockIdx.x * 256 + threadIdx.x;
  if (i >= T_ * 32) return;
  int t = i >> 5, p = i & 31;
  float ang = (float)t * powf(10000.0f, -(float)p * (1.0f / 32.0f));
  tab[i] = sinf(ang);
  tab[T_ * 32 + i] = cosf(ang);
}

// ---------------- shared GEMM core: C[128x128] = A[128xK] * Bm[128xK]^T -------
// LDS: linear dest via global_load_lds, source pre-swizzled (slot ^= row&7),
// reads swizzled -> conflict-free ds_read_b128 (rule #21 both-sides swizzle).
__device__ __forceinline__ void gemm_core(const unsigned short* __restrict__ A,
    const unsigned short* __restrict__ Bm, int m0, int n0,
    unsigned short* lA, unsigned short* lB, f32x4 (&acc)[4][4])
{
  const int tid = threadIdx.x, lane = tid & 63, wave = tid >> 6;
  const int wr = wave >> 1, wc = wave & 1;
  for (int mi = 0; mi < 4; ++mi)
    for (int ni = 0; ni < 4; ++ni)
      acc[mi][ni] = (f32x4){0.f, 0.f, 0.f, 0.f};
  for (int k0 = 0; k0 < 1024; k0 += 64){
    __syncthreads();
#pragma unroll
    for (int p = 0; p < 4; ++p){
      int c = p * 256 + tid, r = c >> 3, s = c & 7;
      int gs = (s ^ (r & 7)) << 3;
      gload16(A + (size_t)(m0 + r) * 1024 + k0 + gs, lA + c * 8);
      gload16(Bm + (size_t)(n0 + r) * 1024 + k0 + gs, lB + c * 8);
    }
    __syncthreads();
#pragma unroll
    for (int kk = 0; kk < 2; ++kk){
      int kslot = kk * 4 + (lane >> 4);
      short8 af[4], bf[4];
#pragma unroll
      for (int mi = 0; mi < 4; ++mi){
        int row = wr * 64 + mi * 16 + (lane & 15);
        af[mi] = *(const short8*)(lA + row * 64 + ((kslot ^ (row & 7)) << 3));
      }
#pragma unroll
      for (int ni = 0; ni < 4; ++ni){
        int row = wc * 64 + ni * 16 + (lane & 15);
        bf[ni] = *(const short8*)(lB + row * 64 + ((kslot ^ (row & 7)) << 3));
      }
#pragma unroll
      for (int mi = 0; mi < 4; ++mi)
#pragma unroll
        for (int ni = 0; ni < 4; ++ni)
          acc[mi][ni] = mfma16(af[mi], bf[ni], acc[mi][ni]);
    }
  }
}

// ---------------- fused QKV projection + bias + RoPE ----------------
// Q is pre-scaled by 0.125*log2(e) (softmax in exp2 domain).
// V is stored TRANSPOSED: [b,h,d,t], vector 8B stores.
__global__ __launch_bounds__(256) void k_qkv(const unsigned short* __restrict__ xb,
    const unsigned short* __restrict__ wqkv,
    const float* __restrict__ bq, const float* __restrict__ bk, const float* __restrict__ bv,
    const float* __restrict__ tab,
    unsigned short* __restrict__ Qw, unsigned short* __restrict__ Kw,
    unsigned short* __restrict__ Vw)
{
  __shared__ alignas(16) unsigned short lA[128 * 64];
  __shared__ alignas(16) unsigned short lB[128 * 64];
  int m0 = blockIdx.y * 128, n0 = blockIdx.x * 128;
  f32x4 acc[4][4];
  gemm_core(xb, wqkv, m0, n0, lA, lB, acc);
  int lane = threadIdx.x & 63, wave = threadIdx.x >> 6;
  int wr = wave >> 1, wc = wave & 1;
  int mat = n0 >> 10;                       // 0=Q 1=K 2=V
  const float* bias = (mat == 0) ? bq : (mat == 1 ? bk : bv);
  const float* st = tab; const float* ct = tab + T_ * 32;
  if (mat < 2){
    unsigned short* Out = (mat == 0) ? Qw : Kw;
    float qs = (mat == 0) ? 0.18033688011116f : 1.0f;   // (1/8)*log2e
    for (int mi = 0; mi < 4; ++mi){
      for (int ni = 0; ni < 4; ++ni){
        int col = n0 + wc * 64 + ni * 16 + (lane & 15);
        int nn = col & 1023, h = nn >> 6, dd = nn & 63;
        float bsv = bias[nn];
        f32x4 v4 = acc[mi][ni];
#pragma unroll
        for (int r = 0; r < 4; ++r){
          int m = m0 + wr * 64 + mi * 16 + ((lane >> 4) << 2) + r;
          int bb = m >> 11, t = m & 2047;
          float v = v4[r] + bsv;
          float u = __shfl_xor(v, 1);       // rope partner col is lane^1
          int p = dd >> 1;
          float sv = st[t * 32 + p], cv = ct[t * 32 + p];
          float res = (dd & 1) ? (u * sv + v * cv) : (v * cv - u * sv);
          Out[((size_t)(bb * H_ + h) * T_ + t) * 64 + dd] = f2bf(res * qs);
        }
      }
    }
  } else {
    for (int mi = 0; mi < 4; ++mi){
      for (int ni = 0; ni < 4; ++ni){
        int col = n0 + wc * 64 + ni * 16 + (lane & 15);
        int nn = col & 1023, h = nn >> 6, dd = nn & 63;
        float bsv = bias[nn];
        int mb = m0 + wr * 64 + mi * 16 + ((lane >> 4) << 2);
        int bb = mb >> 11, t = mb & 2047;
        f32x4 v4 = acc[mi][ni];
        s16x4 o;
#pragma unroll
        for (int r = 0; r < 4; ++r) o[r] = (short)f2bf(v4[r] + bsv);
        *(s16x4*)(Vw + ((size_t)((bb * H_ + h) * 64 + dd)) * T_ + t) = o;
      }
    }
  }
}

// ---------------- flash attention (causal), swapped-QK^T, in-register P -------
__global__ __launch_bounds__(256) void k_attn(const unsigned short* __restrict__ Qw,
    const unsigned short* __restrict__ Kw, const unsigned short* __restrict__ Vt_g,
    unsigned short* __restrict__ ctxb)
{
  __shared__ alignas(16) unsigned short Kl[64 * 64];   // [j][d] swizzled
  __shared__ alignas(16) unsigned short Vl[64 * 64];   // [d][j] swizzled (V^T)
  int qt = (int)gridDim.y - 1 - (int)blockIdx.y;       // heavy blocks first
  int bh = blockIdx.x;
  int tid = threadIdx.x, lane = tid & 63, wave = tid >> 6;
  const unsigned short* Qb = Qw + (size_t)bh * T_ * 64;
  const unsigned short* Kb = Kw + (size_t)bh * T_ * 64;
  const unsigned short* Vb = Vt_g + (size_t)bh * 64 * T_;
  int q0 = qt * 128 + wave * 32;

  short8 qf[2][2];
#pragma unroll
  for (int mi = 0; mi < 2; ++mi){
    const unsigned short* qp = Qb + (size_t)(q0 + mi * 16 + (lane & 15)) * 64 + ((lane >> 4) << 3);
    qf[mi][0] = *(const short8*)qp;
    qf[mi][1] = *(const short8*)(qp + 32);
  }
  float mr[2] = {-1e30f, -1e30f}, lr[2] = {0.f, 0.f};
  f32x4 acc_o[2][4];
#pragma unroll
  for (int mi = 0; mi < 2; ++mi)
#pragma unroll
    for (int df = 0; df < 4; ++df) acc_o[mi][df] = (f32x4){0.f, 0.f, 0.f, 0.f};

  const int src0 = ((lane >> 4) & 1) * 32 + (lane & 15);
  const int src1 = src0 + 16;
  const bool hiHalf = lane >= 32;

  int ntiles = 2 * qt + 2;
  for (int jt = 0; jt < ntiles; ++jt){
    int j0 = jt * 64;
    __syncthreads();
#pragma unroll
    for (int p = 0; p < 2; ++p){
      int c = p * 256 + tid, r = c >> 3, s = c & 7;
      int gs = (s ^ (r & 7)) << 3;
      gload16(Kb + (size_t)(j0 + r) * 64 + gs, Kl + c * 8);
      gload16(Vb + (size_t)r * T_ + j0 + gs, Vl + c * 8);
    }
    __syncthreads();
    if (j0 > q0 + 31) continue;             // wave-level causal skip
    bool need_mask = (j0 + 63 > q0);

    // S^T = K @ Q^T : frag rows = j, cols = q (col = lane&15)
    f32x4 accs[2][4];
#pragma unroll
    for (int mi = 0; mi < 2; ++mi)
#pragma unroll
      for (int jf = 0; jf < 4; ++jf) accs[mi][jf] = (f32x4){0.f, 0.f, 0.f, 0.f};
#pragma unroll
    for (int kk = 0; kk < 2; ++kk){
      int kslot = kk * 4 + (lane >> 4);
      short8 kf[4];
#pragma unroll
      for (int jf = 0; jf < 4; ++jf){
        int row = jf * 16 + (lane & 15);
        kf[jf] = *(const short8*)(Kl + row * 64 + ((kslot ^ (row & 7)) << 3));
      }
#pragma unroll
      for (int mi = 0; mi < 2; ++mi)
#pragma unroll
        for (int jf = 0; jf < 4; ++jf)
          accs[mi][jf] = mfma16(kf[jf], qf[mi][kk], accs[mi][jf]);
    }

    // online softmax per q (all stats lane-local for col q = lane&15)
    unsigned w0[2][4], w1[2][4];
#pragma unroll
    for (int mi = 0; mi < 2; ++mi){
      int qa = q0 + mi * 16 + (lane & 15);
      float s[4][4];
      float mx = -1e30f;
#pragma unroll
      for (int jf = 0; jf < 4; ++jf)
#pragma unroll
        for (int r = 0; r < 4; ++r){
          float sv = accs[mi][jf][r];
          if (need_mask){
            int ja = j0 + jf * 16 + ((lane >> 4) << 2) + r;
            if (ja > qa) sv = -1e30f;
          }
          s[jf][r] = sv;
          mx = fmaxf(mx, sv);
        }
      mx = fmaxf(mx, __shfl_xor(mx, 16));
      mx = fmaxf(mx, __shfl_xor(mx, 32));
      float mn = fmaxf(mr[mi], mx);
      float sc = fexp2(mr[mi] - mn);
      mr[mi] = mn;
      float rs = 0.f;
#pragma unroll
      for (int jf = 0; jf < 4; ++jf)
#pragma unroll
        for (int r = 0; r < 4; ++r){
          float pe = fexp2(s[jf][r] - mn);
          s[jf][r] = pe;
          rs += pe;
        }
      rs += __shfl_xor(rs, 16);
      rs += __shfl_xor(rs, 32);
      lr[mi] = lr[mi] * sc + rs;
#pragma unroll
      for (int df = 0; df < 4; ++df){
        f32x4 a = acc_o[mi][df];
        a[0] *= sc; a[1] *= sc; a[2] *= sc; a[3] *= sc;
        acc_o[mi][df] = a;
      }
#pragma unroll
      for (int jf = 0; jf < 4; ++jf){
        w0[mi][jf] = pk_bf16(s[jf][0], s[jf][1]);
        w1[mi][jf] = pk_bf16(s[jf][2], s[jf][3]);
      }
    }

    // PV: ctx^T[d][q] += V^T[d][j] * P^T[j][q]; B-frag built in-register
#pragma unroll
    for (int kk = 0; kk < 2; ++kk){
      int jslot = kk * 4 + (lane >> 4);
      short8 vf[4];
#pragma unroll
      for (int df = 0; df < 4; ++df){
        int row = df * 16 + (lane & 15);
        vf[df] = *(const short8*)(Vl + row * 64 + ((jslot ^ (row & 7)) << 3));
      }
#pragma unroll
      for (int mi = 0; mi < 2; ++mi){
        unsigned lo0 = (unsigned)__shfl((int)w0[mi][2*kk],   src0);
        unsigned hi0 = (unsigned)__shfl((int)w0[mi][2*kk+1], src0);
        unsigned lo1 = (unsigned)__shfl((int)w1[mi][2*kk],   src0);
        unsigned hi1 = (unsigned)__shfl((int)w1[mi][2*kk+1], src0);
        unsigned lo2 = (unsigned)__shfl((int)w0[mi][2*kk],   src1);
        unsigned hi2 = (unsigned)__shfl((int)w0[mi][2*kk+1], src1);
        unsigned lo3 = (unsigned)__shfl((int)w1[mi][2*kk],   src1);
        unsigned hi3 = (unsigned)__shfl((int)w1[mi][2*kk+1], src1);
        union { unsigned u[4]; short8 v; } pb;
        pb.u[0] = hiHalf ? hi0 : lo0;
        pb.u[1] = hiHalf ? hi1 : lo1;
        pb.u[2] = hiHalf ? hi2 : lo2;
        pb.u[3] = hiHalf ? hi3 : lo3;
#pragma unroll
        for (int df = 0; df < 4; ++df)
          acc_o[mi][df] = mfma16(vf[df], pb.v, acc_o[mi][df]);
      }
    }
  }

  int bb = bh >> 4, h = bh & 15;
#pragma unroll
  for (int mi = 0; mi < 2; ++mi){
    float inv = 1.0f / lr[mi];
    int t = q0 + mi * 16 + (lane & 15);
#pragma unroll
    for (int df = 0; df < 4; ++df){
      int d0 = df * 16 + ((lane >> 4) << 2);
      f32x4 a = acc_o[mi][df];
      s16x4 o;
#pragma unroll
      for (int r = 0; r < 4; ++r) o[r] = (short)f2bf(a[r] * inv);
      *(s16x4*)(ctxb + ((size_t)(bb * T_ + t)) * 1024 + h * 64 + d0) = o;
    }
  }
}

// ---------------- output projection ----------------
__global__ __launch_bounds__(256) void k_oproj(const unsigned short* __restrict__ ctxb,
    const unsigned short* __restrict__ wob, const float* __restrict__ bo,
    float* __restrict__ out)
{
  __shared__ alignas(16) unsigned short lA[128 * 64];
  __shared__ alignas(16) unsigned short lB[128 * 64];
  int m0 = blockIdx.y * 128, n0 = blockIdx.x * 128;
  f32x4 acc[4][4];
  gemm_core(ctxb, wob, m0, n0, lA, lB, acc);
  int lane = threadIdx.x & 63, wave = threadIdx.x >> 6;
  int wr = wave >> 1, wc = wave & 1;
  for (int mi = 0; mi < 4; ++mi)
    for (int ni = 0; ni < 4; ++ni){
      int col = n0 + wc * 64 + ni * 16 + (lane & 15);
      float bsv = bo[col];
      f32x4 v4 = acc[mi][ni];
#pragma unroll
      for (int r = 0; r < 4; ++r){
        int m = m0 + wr * 64 + mi * 16 + ((lane >> 4) << 2) + r;
        out[(size_t)m * 1024 + col] = v4[r] + bsv;
      }
    }
}

extern "C" void kernel_launch(void* const* d_in, const int* in_sizes, int n_in,
                              void* d_out, int out_size, void* d_ws, size_t ws_size,
                              hipStream_t stream)
{
  const float* x  = (const float*)d_in[0];
  const float* wq = (const float*)d_in[1];
  const float* bq = (const float*)d_in[2];
  const float* wk = (const float*)d_in[3];
  const float* bk = (const float*)d_in[4];
  const float* wv = (const float*)d_in[5];
  const float* bv = (const float*)d_in[6];
  const float* wo = (const float*)d_in[7];
  const float* bo = (const float*)d_in[8];
  char* w = (char*)d_ws;
  unsigned short* xb   = (unsigned short*)(w);               // 8 MiB  [4096][1024]
  unsigned short* wqkv = (unsigned short*)(w + (8 << 20));   // 6 MiB  [3072][1024]
  unsigned short* wob  = (unsigned short*)(w + (14 << 20));  // 2 MiB
  unsigned short* Qw   = (unsigned short*)(w + (16 << 20));  // 8 MiB  [B,H,T,DK]
  unsigned short* Kw   = (unsigned short*)(w + (24 << 20));  // 8 MiB  [B,H,T,DK]
  unsigned short* Vw   = (unsigned short*)(w + (32 << 20));  // 8 MiB  [B,H,DK,T] (transposed!)
  unsigned short* ctxb = (unsigned short*)(w + (40 << 20));  // 8 MiB  [B,T,D]
  float* tab           = (float*)(w + (48 << 20));           // 512 KiB sin|cos

  k_prep<<<8192, 256, 0, stream>>>(x, wq, wk, wv, wo, xb, wqkv, wob);
  k_rope<<<256, 256, 0, stream>>>(tab);
  k_qkv<<<dim3(24, 32), 256, 0, stream>>>(xb, wqkv, bq, bk, bv, tab, Qw, Kw, Vw);
  k_attn<<<dim3(32, 16), 256, 0, stream>>>(Qw, Kw, Vw, ctxb);
  k_oproj<<<dim3(8, 32), 256, 0, stream>>>(ctxb, wob, bo, (float*)d_out);
}